// Round 3
// baseline (109.345 us; speedup 1.0000x reference)
//
#include <hip/hip_runtime.h>
#include <hip/hip_bf16.h>
#include <math.h>

#define N    8192
#define DIM  64
#define KSEL 32
#define RPW  8      // rows per wave in kernel B

// ---------------------------------------------------------------------------
// Kernel A v2: v = tanh(3 * (emb[idx] @ W^T + b)), LDS-free.
// Lane d holds W[d,:] in 64 VGPRs (16 b128 global loads, L1/L2-hot).
// Gathered emb rows are wave-uniform -> scalar loads (s_load) feed the FMAs
// as SGPR operands. 4 rows per wave, 16 rows/block, grid = 2*N/16 = 1024.
// blockIdx.x & 1 selects emb1->v1 vs emb2->v2.
// ---------------------------------------------------------------------------
__global__ __launch_bounds__(256) void embed_linear_tanh(
    const int*   __restrict__ idx,
    const float* __restrict__ emb1,
    const float* __restrict__ emb2,
    const float* __restrict__ W,     // [DIM][DIM], out[d] = dot(e, W[d,:]) + b[d]
    const float* __restrict__ b,
    float* __restrict__ v1,
    float* __restrict__ v2)
{
    const int t = threadIdx.x;
    const int m = blockIdx.x & 1;
    const int rowbase = (blockIdx.x >> 1) * 16;
    const float* emb  = m ? emb2 : emb1;
    float*       vout = m ? v2   : v1;

    const int d  = t & 63;                                    // lane = output dim
    const int wu = __builtin_amdgcn_readfirstlane(t >> 6);    // wave id, forced SGPR

    // W row d -> 16 float4 in VGPRs
    float4 Wr[16];
    {
        const float4* W4 = (const float4*)(W + (size_t)d * DIM);
        #pragma unroll
        for (int k4 = 0; k4 < 16; ++k4) Wr[k4] = W4[k4];
    }
    const float bias = b[d];

    #pragma unroll
    for (int rr = 0; rr < 4; ++rr) {
        const int r = rowbase + wu * 4 + rr;                  // uniform
        const int g = idx[r];                                 // uniform addr -> s_load
        const float* e = emb + (size_t)g * DIM;               // uniform row pointer
        float acc = bias;
        #pragma unroll
        for (int k4 = 0; k4 < 16; ++k4) {
            float4 wv = Wr[k4];
            acc += e[k4*4+0] * wv.x;   // e[*]: scalar loads, SGPR operand in FMA
            acc += e[k4*4+1] * wv.y;
            acc += e[k4*4+2] * wv.z;
            acc += e[k4*4+3] * wv.w;
        }
        vout[(size_t)r * DIM + d] = tanhf(3.0f * acc);
    }
}

// ---------------------------------------------------------------------------
// Kernel B v3: register-tiled column census, scalar-path row vectors.
// Per row i, find the 32 lowest columns j with tanhf(3*a[i,j]) == 1.0f
// (== jax top_k(adj,32)+sort: ties at 1.0 break to lowest index).
//
// Block = 256 (4 waves) x 8 rows/wave = 32 rows/block, grid = 256 (1/CU).
// Per 64-col chunk: block stages column rows to LDS ([k4][col] float4,
// conflict-free b128); each lane pulls ITS column into 128 VGPRs once and
// reuses it for 8 rows; row vectors read via wave-uniform s_loads (no LDS).
// Early exit via __syncthreads_and. Serial exact fallback (P ~ 0) kept.
// ---------------------------------------------------------------------------
__global__ __launch_bounds__(256) void build_graph(
    const float* __restrict__ v1,
    const float* __restrict__ v2,
    float* __restrict__ out_rows,
    float* __restrict__ out_cols,
    float* __restrict__ out_data)
{
    __shared__ float4 c1v[16][64];   // [k4][col]: lane l -> start bank 4l%32, conflict-free
    __shared__ float4 c2v[16][64];
    __shared__ int    colbuf[32][KSEL];

    const int t = threadIdx.x;
    const int l = t & 63;
    const int wu = __builtin_amdgcn_readfirstlane(t >> 6);    // wave id, SGPR
    const int rowbase = blockIdx.x * 32;

    int  cnt[RPW];
    #pragma unroll
    for (int rr = 0; rr < RPW; ++rr) cnt[rr] = 0;
    bool done = false;
    const int sr = t >> 2;           // staging: column row 0..63
    const int sq = t & 3;            // staging: 64B segment within row

    for (int cc = 0; cc < N / 64; ++cc) {
        const int jbase = cc * 64;
        // ---- cooperative staging: 64 column rows of v1,v2 -> LDS ----
        {
            const float4* p1 = (const float4*)(v1 + (size_t)(jbase + sr) * DIM) + sq * 4;
            const float4* p2 = (const float4*)(v2 + (size_t)(jbase + sr) * DIM) + sq * 4;
            #pragma unroll
            for (int s = 0; s < 4; ++s) {
                c1v[sq * 4 + s][sr] = p1[s];
                c2v[sq * 4 + s][sr] = p2[s];
            }
        }
        __syncthreads();

        if (!done) {
            // pull column (jbase+l) into registers: 32 conflict-free b128
            float4 c1r[16], c2r[16];
            #pragma unroll
            for (int k4 = 0; k4 < 16; ++k4) { c1r[k4] = c1v[k4][l]; c2r[k4] = c2v[k4][l]; }

            bool all_done = true;
            #pragma unroll
            for (int rr = 0; rr < RPW; ++rr) {
                if (cnt[rr] < KSEL) {                 // wave-uniform branch
                    const int wrow = wu * RPW + rr;
                    const int i = rowbase + wrow;     // uniform
                    const float* r1 = v1 + (size_t)i * DIM;   // uniform -> s_load
                    const float* r2 = v2 + (size_t)i * DIM;
                    float d1 = 0.f, d2 = 0.f;
                    #pragma unroll
                    for (int k4 = 0; k4 < 16; ++k4) {
                        float4 b2 = c2r[k4];
                        d1 += r1[k4*4+0] * b2.x + r1[k4*4+1] * b2.y
                            + r1[k4*4+2] * b2.z + r1[k4*4+3] * b2.w;
                        float4 b1 = c1r[k4];
                        d2 += r2[k4*4+0] * b1.x + r2[k4*4+1] * b1.y
                            + r2[k4*4+2] * b1.z + r2[k4*4+3] * b1.w;
                    }
                    float a    = d1 - d2;
                    float adjv = tanhf(3.0f * a);
                    bool  sat  = (adjv == 1.0f);      // fp32 tanh saturation
                    unsigned long long mask = __ballot(sat);
                    int rank = (int)__popcll(mask & ((1ull << l) - 1ull));
                    if (sat && (cnt[rr] + rank) < KSEL) colbuf[wrow][cnt[rr] + rank] = jbase + l;
                    cnt[rr] += (int)__popcll(mask);
                    if (cnt[rr] < KSEL) all_done = false;
                }
            }
            if (all_done) done = true;
        }
        if (__syncthreads_and(done ? 1 : 0)) break;   // fused barrier + all-reduce
    }

    #pragma unroll
    for (int rr = 0; rr < RPW; ++rr) {
        const int wrow = wu * RPW + rr;
        const int i = rowbase + wrow;
        if (cnt[rr] >= KSEL) {
            if (l < KSEL) {
                int col = colbuf[wrow][l];       // ascending by construction
                size_t o = (size_t)i * KSEL + l;
                out_rows[o] = (float)i;
                out_cols[o] = (float)col;
                out_data[o] = 1.0f;              // saturated value, exact
            }
        } else if (l == 0) {
            // exact serial fallback: top-32 by (value desc, index asc), then col-sort.
            float bv[KSEL]; int bc[KSEL];
            #pragma unroll
            for (int k = 0; k < KSEL; ++k) { bv[k] = -1.0f; bc[k] = 0; }
            for (int j = 0; j < N; ++j) {
                float d1 = 0.f, d2 = 0.f;
                for (int k = 0; k < DIM; ++k) {
                    d1 += v1[(size_t)i * DIM + k] * v2[(size_t)j * DIM + k];
                    d2 += v2[(size_t)i * DIM + k] * v1[(size_t)j * DIM + k];
                }
                float adjv = fmaxf(tanhf(3.0f * (d1 - d2)), 0.0f);
                if (adjv > bv[KSEL - 1]) {       // strict: earlier equal index wins
                    int p = KSEL - 1;
                    while (p > 0 && bv[p - 1] < adjv) {
                        bv[p] = bv[p - 1]; bc[p] = bc[p - 1]; --p;
                    }
                    bv[p] = adjv; bc[p] = j;
                }
            }
            for (int x = 1; x < KSEL; ++x) {     // sort by column ascending
                float tv = bv[x]; int tc = bc[x]; int y = x - 1;
                while (y >= 0 && bc[y] > tc) { bv[y+1] = bv[y]; bc[y+1] = bc[y]; --y; }
                bv[y + 1] = tv; bc[y + 1] = tc;
            }
            for (int k = 0; k < KSEL; ++k) {
                size_t o = (size_t)i * KSEL + k;
                out_rows[o] = (float)i;
                out_cols[o] = (float)bc[k];
                out_data[o] = bv[k];
            }
        }
    }
}

// ---------------------------------------------------------------------------
extern "C" void kernel_launch(void* const* d_in, const int* in_sizes, int n_in,
                              void* d_out, int out_size, void* d_ws, size_t ws_size,
                              hipStream_t stream) {
    const int*   idx  = (const int*)  d_in[0];
    const float* emb1 = (const float*)d_in[1];
    const float* emb2 = (const float*)d_in[2];
    const float* w1   = (const float*)d_in[3];
    const float* b1   = (const float*)d_in[4];
    // d_in[5], d_in[6] = lin2_w / lin2_b -- unused by the reference (faithful).

    float* v1 = (float*)d_ws;                  // [N][DIM] fp32
    float* v2 = v1 + (size_t)N * DIM;          // [N][DIM] fp32  (4 MB total)

    float* out      = (float*)d_out;           // [2*N*K index | N*K data], all fp32
    float* out_rows = out;
    float* out_cols = out + (size_t)N * KSEL;
    float* out_data = out + (size_t)2 * N * KSEL;

    embed_linear_tanh<<<2 * N / 16, 256, 0, stream>>>(idx, emb1, emb2, w1, b1, v1, v2);
    build_graph<<<N / 32, 256, 0, stream>>>(v1, v2, out_rows, out_cols, out_data);
}

// Round 4
// 92.831 us; speedup vs baseline: 1.1779x; 1.1779x over previous
//
#include <hip/hip_runtime.h>
#include <hip/hip_bf16.h>
#include <math.h>

#define N    8192
#define DIM  64
#define KSEL 32

// ---------------------------------------------------------------------------
// Kernel A (R2 known-good): v = tanh(3 * (emb[idx] @ W^T + b))
// block = 256 threads; each block: 16 rows x 64 dims of one matrix.
// grid.x = 2*N/16 = 1024 ; blockIdx.x&1 selects matrix.
// ---------------------------------------------------------------------------
__global__ __launch_bounds__(256) void embed_linear_tanh(
    const int*   __restrict__ idx,
    const float* __restrict__ emb1,
    const float* __restrict__ emb2,
    const float* __restrict__ W,     // [DIM][DIM], out[d] = dot(e, W[d,:]) + b[d]
    const float* __restrict__ b,
    float* __restrict__ v1,
    float* __restrict__ v2)
{
    __shared__ float Wp[DIM][DIM + 1];   // +1 pad: lane l reads Wp[l][k] -> bank (l+k)%32, 2-way = free
    __shared__ float e[16][DIM];         // broadcast reads (same addr per wave) -> no pad needed

    const int t = threadIdx.x;
    const int m = blockIdx.x & 1;                 // 0: emb1->v1, 1: emb2->v2
    const int rowbase = (blockIdx.x >> 1) * 16;
    const float* emb  = m ? emb2 : emb1;
    float*       vout = m ? v2   : v1;

    // stage W (4096 floats): 256 threads * 4 float4
    {
        const float4* W4 = (const float4*)W;
        #pragma unroll
        for (int s = 0; s < 4; ++s) {
            int e4 = t + s * 256;          // 0..1023
            float4 wv = W4[e4];
            int d = e4 >> 4;
            int k = (e4 & 15) * 4;
            Wp[d][k]   = wv.x; Wp[d][k+1] = wv.y;
            Wp[d][k+2] = wv.z; Wp[d][k+3] = wv.w;
        }
    }
    // stage 16 gathered emb rows (1024 floats): thread t -> row t>>4, float4 seg t&15
    {
        int r = t >> 4, seg = t & 15;
        int g = idx[rowbase + r];
        float4 x = ((const float4*)(emb + (size_t)g * DIM))[seg];
        e[r][seg*4]   = x.x; e[r][seg*4+1] = x.y;
        e[r][seg*4+2] = x.z; e[r][seg*4+3] = x.w;
    }
    __syncthreads();

    const int d  = t & 63;   // output dim (= lane)
    const int r0 = t >> 6;   // wave index
    const float bias = b[d];
    #pragma unroll
    for (int rr = 0; rr < 4; ++rr) {
        int r = r0 + rr * 4;               // local row; same r across a wave -> e[] broadcast
        float acc = bias;
        #pragma unroll
        for (int k = 0; k < DIM; ++k) acc += e[r][k] * Wp[d][k];
        vout[(size_t)(rowbase + r) * DIM + d] = tanhf(3.0f * acc);
    }
}

// ---------------------------------------------------------------------------
// Kernel B v4 = R2 structure + scalar-path row vectors (ONE change vs R2).
// Per row i, find the 32 lowest columns j with tanhf(3*a[i,j]) == 1.0f
// (== jax top_k(adj,32)+sort: ties at 1.0 break to lowest index).
//
// Block = 256 threads (4 waves); wave owns 4 rows -> 16 rows/block,
// grid = 512 (2 blocks/CU, 8 waves/CU — R2's proven occupancy).
// Per 64-column chunk: block stages v1/v2 column rows into LDS
// ([k4][col] float4, conflict-free b128), each lane pulls ITS column into
// 128 VGPRs ONCE, then loops the wave's 4 rows. Row vectors are read via
// wave-uniform pointers -> s_load on the scalar/constant-cache pipe
// (replaces R2's vi LDS broadcasts — the largest LDS-pipe term).
// Serial exact top-k fallback if a row has <32 saturated entries (P ~ 0).
// ---------------------------------------------------------------------------
__global__ __launch_bounds__(256, 2) void build_graph(
    const float* __restrict__ v1,
    const float* __restrict__ v2,
    float* __restrict__ out_rows,
    float* __restrict__ out_cols,
    float* __restrict__ out_data)
{
    __shared__ float4 c1v[16][64];   // [k4][col] : lane l -> start bank 4l%32, conflict-free
    __shared__ float4 c2v[16][64];
    __shared__ int    colbuf[16][KSEL];
    __shared__ int    wdone[4];

    const int t = threadIdx.x;
    const int l = t & 63;            // lane
    const int w = __builtin_amdgcn_readfirstlane(t >> 6);   // wave 0..3, forced SGPR
    const int rowbase = blockIdx.x * 16;

    if (l == 0) wdone[w] = 0;
    __syncthreads();

    int  cnt[4] = {0, 0, 0, 0};      // per-row saturated-count (wave-uniform)
    bool done = false;
    const int sr = t >> 2;           // staging: column row 0..63
    const int sq = t & 3;            // staging: 64B segment within row

    for (int cc = 0; cc < N / 64; ++cc) {
        const int jbase = cc * 64;
        // ---- cooperative staging: 64 column rows of v1,v2 -> LDS ----
        {
            const float4* p1 = (const float4*)(v1 + (size_t)(jbase + sr) * DIM) + sq * 4;
            const float4* p2 = (const float4*)(v2 + (size_t)(jbase + sr) * DIM) + sq * 4;
            #pragma unroll
            for (int s = 0; s < 4; ++s) {
                c1v[sq * 4 + s][sr] = p1[s];
                c2v[sq * 4 + s][sr] = p2[s];
            }
        }
        __syncthreads();

        if (!done) {
            // pull column (jbase+l) into registers: 32 conflict-free b128
            float4 c1r[16], c2r[16];
            #pragma unroll
            for (int k4 = 0; k4 < 16; ++k4) { c1r[k4] = c1v[k4][l]; c2r[k4] = c2v[k4][l]; }

            bool all_done = true;
            #pragma unroll
            for (int rr = 0; rr < 4; ++rr) {
                if (cnt[rr] < KSEL) {                 // wave-uniform branch
                    const int wrow = w * 4 + rr;
                    const int i = rowbase + wrow;                 // uniform
                    const float* __restrict__ r1 = v1 + (size_t)i * DIM;  // uniform -> s_load
                    const float* __restrict__ r2 = v2 + (size_t)i * DIM;
                    float d1 = 0.f, d2 = 0.f;
                    #pragma unroll
                    for (int k4 = 0; k4 < 16; ++k4) {
                        float4 b2 = c2r[k4];
                        d1 += r1[k4*4+0] * b2.x + r1[k4*4+1] * b2.y
                            + r1[k4*4+2] * b2.z + r1[k4*4+3] * b2.w;
                        float4 b1 = c1r[k4];
                        d2 += r2[k4*4+0] * b1.x + r2[k4*4+1] * b1.y
                            + r2[k4*4+2] * b1.z + r2[k4*4+3] * b1.w;
                    }
                    float a    = d1 - d2;
                    float adjv = tanhf(3.0f * a);
                    bool  sat  = (adjv == 1.0f);      // fp32 tanh saturation
                    unsigned long long mask = __ballot(sat);
                    int rank = (int)__popcll(mask & ((1ull << l) - 1ull));
                    if (sat && (cnt[rr] + rank) < KSEL) colbuf[wrow][cnt[rr] + rank] = jbase + l;
                    cnt[rr] += (int)__popcll(mask);
                    if (cnt[rr] < KSEL) all_done = false;
                }
            }
            if (all_done) { done = true; if (l == 0) wdone[w] = 1; }
        }
        __syncthreads();
        if (wdone[0] && wdone[1] && wdone[2] && wdone[3]) break;  // uniform
    }

    #pragma unroll
    for (int rr = 0; rr < 4; ++rr) {
        const int wrow = w * 4 + rr;
        const int i = rowbase + wrow;
        if (cnt[rr] >= KSEL) {
            if (l < KSEL) {
                int col = colbuf[wrow][l];       // ascending by construction
                size_t o = (size_t)i * KSEL + l;
                out_rows[o] = (float)i;
                out_cols[o] = (float)col;
                out_data[o] = 1.0f;              // saturated value, exact
            }
        } else if (l == 0) {
            // exact serial fallback: top-32 by (value desc, index asc), then col-sort.
            float bv[KSEL]; int bc[KSEL];
            #pragma unroll
            for (int k = 0; k < KSEL; ++k) { bv[k] = -1.0f; bc[k] = 0; }
            for (int j = 0; j < N; ++j) {
                float d1 = 0.f, d2 = 0.f;
                for (int k = 0; k < DIM; ++k) {
                    d1 += v1[(size_t)i * DIM + k] * v2[(size_t)j * DIM + k];
                    d2 += v2[(size_t)i * DIM + k] * v1[(size_t)j * DIM + k];
                }
                float adjv = fmaxf(tanhf(3.0f * (d1 - d2)), 0.0f);
                if (adjv > bv[KSEL - 1]) {       // strict: earlier equal index wins
                    int p = KSEL - 1;
                    while (p > 0 && bv[p - 1] < adjv) {
                        bv[p] = bv[p - 1]; bc[p] = bc[p - 1]; --p;
                    }
                    bv[p] = adjv; bc[p] = j;
                }
            }
            for (int x = 1; x < KSEL; ++x) {     // sort by column ascending
                float tv = bv[x]; int tc = bc[x]; int y = x - 1;
                while (y >= 0 && bc[y] > tc) { bv[y+1] = bv[y]; bc[y+1] = bc[y]; --y; }
                bv[y + 1] = tv; bc[y + 1] = tc;
            }
            for (int k = 0; k < KSEL; ++k) {
                size_t o = (size_t)i * KSEL + k;
                out_rows[o] = (float)i;
                out_cols[o] = (float)bc[k];
                out_data[o] = bv[k];
            }
        }
    }
}

// ---------------------------------------------------------------------------
extern "C" void kernel_launch(void* const* d_in, const int* in_sizes, int n_in,
                              void* d_out, int out_size, void* d_ws, size_t ws_size,
                              hipStream_t stream) {
    const int*   idx  = (const int*)  d_in[0];
    const float* emb1 = (const float*)d_in[1];
    const float* emb2 = (const float*)d_in[2];
    const float* w1   = (const float*)d_in[3];
    const float* b1   = (const float*)d_in[4];
    // d_in[5], d_in[6] = lin2_w / lin2_b -- unused by the reference (faithful).

    float* v1 = (float*)d_ws;                  // [N][DIM] fp32
    float* v2 = v1 + (size_t)N * DIM;          // [N][DIM] fp32  (4 MB total)

    float* out      = (float*)d_out;           // [2*N*K index | N*K data], all fp32
    float* out_rows = out;
    float* out_cols = out + (size_t)N * KSEL;
    float* out_data = out + (size_t)2 * N * KSEL;

    embed_linear_tanh<<<2 * N / 16, 256, 0, stream>>>(idx, emb1, emb2, w1, b1, v1, v2);
    build_graph<<<N / 16, 256, 0, stream>>>(v1, v2, out_rows, out_cols, out_data);
}